// Round 11
// baseline (96.275 us; speedup 1.0000x reference)
//
#include <hip/hip_runtime.h>
#include <utility>

#define IMG_H 512
#define IMG_W 512

typedef _Float16 h2 __attribute__((ext_vector_type(2)));
typedef _Float16 h16 __attribute__((ext_vector_type(16)));

__device__ __forceinline__ h2 h2min(h2 a, h2 b) { return __builtin_elementwise_min(a, b); }
__device__ __forceinline__ h2 h2max(h2 a, h2 b) { return __builtin_elementwise_max(a, b); }

// ---------------------------------------------------------------------------
// Round 11: LDS STAGING. r6 evidence: VALUBusy 30%, ~450 GB/s, kernel ~70%
// stalled — and rounds 7-10 proved the stall is insensitive to VALU count /
// registers / code shape. Diagnosis: the compiler sinks the 32 global loads
// to first use, serializing ~10 HBM/L2 latency episodes through the sort.
// Fix: block-cooperative coalesced load -> f16 -> LDS tile, one barrier,
// then conflict-free ds_read_b128 (lane-contiguous) feeds the sort; LDS
// halo rows/cols hold the zero padding. Sort program = r10 (mov-free,
// pruned, regalloc'd), unchanged.
// kinds: 0 ce(a,b)  1 mov a<-b  2 load a<-cols[b]  3 store med[a]<-v[b]
//        4 a=min(a,b)  5 b=max(a,b)  7 c=max(a,b)
// ---------------------------------------------------------------------------
struct Op { int kind, a, b, c; };
constexpr int NSLOT = 512;
constexpr int MAXOPS = 4096;
struct Prog { Op ops[MAXOPS]; int n; int nphys; bool ok; };

constexpr int pow2ceil(int x) { int p = 1; while (p < x) p += p; return p; }

struct Run { int s[48]; int len; };

struct Builder {
    Op ops[MAXOPS] = {};
    int n = 0;
    int nv = 0;
    bool ok = true;

    constexpr void emit(int k, int a, int b, int c) {
        if (n < MAXOPS) ops[n++] = Op{k, a, b, c}; else ok = false;
    }
    constexpr int fresh() {
        if (nv < NSLOT) return nv++;
        ok = false; return 0;
    }
    constexpr Run load_col(int c) {
        Run r{}; r.len = 7;
        for (int i = 0; i < 7; ++i) { r.s[i] = fresh(); emit(2, r.s[i], c * 7 + i, 0); }
        for (int p = 1; p < 7; p += p)
            for (int k = p; k > 0; k /= 2)
                for (int j = k % p; j + k < 7; j += k + k)
                    for (int i = 0; i < k; ++i)
                        if (i + j + k < 7 && (i + j) / (p + p) == (i + j + k) / (p + p))
                            emit(0, r.s[i + j], r.s[i + j + k], 0);
        return r;
    }
    constexpr Run copy(const Run& a) {
        Run r{}; r.len = a.len;
        for (int i = 0; i < a.len; ++i) { r.s[i] = fresh(); emit(1, r.s[i], a.s[i], 0); }
        return r;
    }
    constexpr Run merge(const Run& A, const Run& B) {
        int P = pow2ceil(A.len > B.len ? A.len : B.len);
        if (A.len > P || B.len > P || 2 * P > 96) { ok = false; }
        int map[96] = {};
        for (int i = 0; i < 2 * P; ++i) map[i] = -1;
        for (int i = 0; i < A.len; ++i) map[i] = A.s[i];
        for (int i = 0; i < B.len; ++i) map[P + i] = B.s[i];
        for (int k = P; k > 0; k /= 2)
            for (int j = k % P; j + k < 2 * P; j += k + k)
                for (int i = 0; i < k; ++i) {
                    int x = i + j, y = i + j + k;
                    int a = map[x], b = map[y];
                    if (a >= 0 && b >= 0) emit(0, a, b, 0);
                    else if (a < 0 && b >= 0) { map[x] = b; map[y] = -1; }
                }
        Run r{}; r.len = A.len + B.len;
        for (int i = 0; i < r.len; ++i) { if (map[i] < 0) ok = false; r.s[i] = map[i]; }
        for (int i = r.len; i < 2 * P; ++i) if (map[i] >= 0) ok = false;
        return r;
    }
    constexpr void select49(const Run& A, const Run& B, int o) {
        if (A.len != 42 || B.len != 7) ok = false;
        int T[7] = {};
        for (int t = 0; t < 7; ++t) {
            T[t] = fresh();
            emit(7, A.s[17 + t], B.s[6 - t], T[t]);
        }
        emit(4, T[0], T[1], 0); emit(4, T[2], T[3], 0);
        emit(4, T[4], T[5], 0); emit(4, T[6], A.s[24], 0);
        emit(4, T[0], T[2], 0); emit(4, T[4], T[6], 0);
        emit(4, T[0], T[4], 0);
        emit(3, o, T[0], 0);
    }
};

constexpr Prog build() {
    Builder b{};
    Run g1 = b.load_col(1), g2 = b.load_col(2), g3 = b.load_col(3),
        g4 = b.load_col(4), g5 = b.load_col(5), g6 = b.load_col(6),
        g7 = b.load_col(7), g8 = b.load_col(8);
    Run g2c = b.copy(g2), g4c = b.copy(g4), g6c = b.copy(g6);

    Run M12 = b.merge(g1, g2c);
    Run M34 = b.merge(g3, g4c);
    Run M56 = b.merge(g5, g6c);
    Run M56b = b.copy(M56);
    Run C28A = b.merge(M34, M56);
    Run C28Ac = b.copy(C28A);
    Run C42A = b.merge(C28Ac, M12);
    Run g0 = b.load_col(0);
    b.select49(C42A, g0, 0);
    b.select49(C42A, g7, 1);

    Run M78 = b.merge(g7, g8);
    Run M78b = b.copy(M78);
    Run C42B = b.merge(C28A, M78);
    Run g9 = b.load_col(9);
    b.select49(C42B, g2, 2);
    b.select49(C42B, g9, 3);

    Run g10 = b.load_col(10);
    Run M910 = b.merge(g9, g10);
    Run C28B = b.merge(M78b, M910);
    Run C28Bc = b.copy(C28B);
    Run C42C = b.merge(C28Bc, M56b);
    Run g11 = b.load_col(11);
    b.select49(C42C, g4, 4);
    b.select49(C42C, g11, 5);

    Run g12 = b.load_col(12);
    Run M1112 = b.merge(g11, g12);
    Run C42D = b.merge(C28B, M1112);
    Run g13 = b.load_col(13);
    b.select49(C42D, g6, 6);
    b.select49(C42D, g13, 7);

    // ---- backward prune + min/max degradation ----
    Prog p{};
    bool needed[NSLOT] = {};
    int kindr[MAXOPS] = {};
    bool keep[MAXOPS] = {};
    for (int t = b.n - 1; t >= 0; --t) {
        Op o = b.ops[t];
        if (o.kind == 3) { keep[t] = true; kindr[t] = 3; needed[o.b] = true; }
        else if (o.kind == 0) {
            bool na = needed[o.a], nb = needed[o.b];
            if (na && nb)      { keep[t] = true; kindr[t] = 0; }
            else if (na)       { keep[t] = true; kindr[t] = 4; needed[o.b] = true; }
            else if (nb)       { keep[t] = true; kindr[t] = 5; needed[o.a] = true; }
        } else if (o.kind == 1) {
            if (needed[o.a]) { keep[t] = true; kindr[t] = 1; needed[o.a] = false; needed[o.b] = true; }
        } else if (o.kind == 2) {
            if (needed[o.a]) { keep[t] = true; kindr[t] = 2; needed[o.a] = false; }
        } else if (o.kind == 4) {
            if (needed[o.a]) { keep[t] = true; kindr[t] = 4; needed[o.b] = true; }
        } else if (o.kind == 5) {
            if (needed[o.b]) { keep[t] = true; kindr[t] = 5; needed[o.a] = true; }
        } else if (o.kind == 7) {
            if (needed[o.c]) { keep[t] = true; kindr[t] = 7; needed[o.c] = false;
                               needed[o.a] = true; needed[o.b] = true; }
        }
    }
    p.n = 0;
    for (int t = 0; t < b.n; ++t)
        if (keep[t]) { p.ops[p.n] = b.ops[t]; p.ops[p.n].kind = kindr[t]; ++p.n; }
    p.ok = b.ok;

    // ---- liveness / last-use flags ----
    bool live[NSLOT] = {};
    bool lu_a[MAXOPS] = {};
    bool lu_b[MAXOPS] = {};
    for (int t = p.n - 1; t >= 0; --t) {
        Op o = p.ops[t];
        if (o.kind == 0 || o.kind == 4 || o.kind == 5 || o.kind == 7) {
            lu_a[t] = !live[o.a]; lu_b[t] = !live[o.b];
        } else if (o.kind == 1 || o.kind == 3) {
            lu_b[t] = !live[o.b];
        }
        if (o.kind == 0) { live[o.a] = false; live[o.b] = false; }
        else if (o.kind == 1 || o.kind == 2 || o.kind == 4) live[o.a] = false;
        else if (o.kind == 5) live[o.b] = false;
        else if (o.kind == 7) live[o.c] = false;
        if (o.kind == 0 || o.kind == 4 || o.kind == 5 || o.kind == 7) {
            live[o.a] = true; live[o.b] = true;
        } else if (o.kind == 1 || o.kind == 3) live[o.b] = true;
    }
    for (int t = 0; t < p.n; ++t) {
        Op o = p.ops[t];
        if (o.kind == 0 && (lu_a[t] || lu_b[t])) p.ok = false;
        if (o.kind == 4 && lu_a[t]) p.ok = false;
        if (o.kind == 5 && lu_b[t]) p.ok = false;
    }
    // ---- linear-scan regalloc ----
    int phys[NSLOT] = {};
    bool bound[NSLOT] = {};
    int freelist[NSLOT] = {};
    int nfree = 0, nphys = 0;
    for (int t = 0; t < p.n; ++t) {
        Op o = p.ops[t];
        if (o.kind == 0) {
            if (!bound[o.a] || !bound[o.b]) p.ok = false;
            p.ops[t].a = phys[o.a]; p.ops[t].b = phys[o.b];
        } else if (o.kind == 4) {
            if (!bound[o.a] || !bound[o.b]) p.ok = false;
            p.ops[t].a = phys[o.a]; p.ops[t].b = phys[o.b];
            if (lu_b[t]) { freelist[nfree++] = phys[o.b]; bound[o.b] = false; }
        } else if (o.kind == 5) {
            if (!bound[o.a] || !bound[o.b]) p.ok = false;
            p.ops[t].a = phys[o.a]; p.ops[t].b = phys[o.b];
            if (lu_a[t]) { freelist[nfree++] = phys[o.a]; bound[o.a] = false; }
        } else if (o.kind == 7) {
            if (!bound[o.a] || !bound[o.b]) p.ok = false;
            p.ops[t].a = phys[o.a]; p.ops[t].b = phys[o.b];
            if (lu_a[t]) { freelist[nfree++] = phys[o.a]; bound[o.a] = false; }
            if (lu_b[t]) { freelist[nfree++] = phys[o.b]; bound[o.b] = false; }
            int pc = (nfree > 0) ? freelist[--nfree] : nphys++;
            phys[o.c] = pc; bound[o.c] = true;
            p.ops[t].c = pc;
        } else if (o.kind == 1) {
            if (!bound[o.b]) p.ok = false;
            int pb = phys[o.b];
            p.ops[t].b = pb;
            if (lu_b[t]) { freelist[nfree++] = pb; bound[o.b] = false; }
            int pa = (nfree > 0) ? freelist[--nfree] : nphys++;
            phys[o.a] = pa; bound[o.a] = true;
            p.ops[t].a = pa;
        } else if (o.kind == 2) {
            int pa = (nfree > 0) ? freelist[--nfree] : nphys++;
            phys[o.a] = pa; bound[o.a] = true;
            p.ops[t].a = pa;
        } else {
            if (!bound[o.b]) p.ok = false;
            p.ops[t].b = phys[o.b];
            if (lu_b[t]) { freelist[nfree++] = phys[o.b]; bound[o.b] = false; }
        }
        if (nphys > NSLOT || nfree > NSLOT) p.ok = false;
    }
    p.nphys = nphys;
    return p;
}

constexpr Prog PROG = build();
static_assert(PROG.ok, "program build failed");
static_assert(PROG.n > 300 && PROG.n < 2400, "op count out of range");
static_assert(PROG.nphys > 0 && PROG.nphys <= 256, "regalloc blew up");

// ---- banked physical frame: every alloca <= 64 elements ----
template <int P>
__device__ __forceinline__ h2& vslot(h2* v0, h2* v1, h2* v2, h2* v3) {
    if constexpr (P < 64) return v0[P];
    else if constexpr (P < 128) return v1[P - 64];
    else if constexpr (P < 192) return v2[P - 128];
    else return v3[P - 192];
}
template <int P>
__device__ __forceinline__ h2 cslot(const h2* c0, const h2* c1) {
    if constexpr (P < 49) return c0[P];
    else return c1[P - 49];
}

template <int I>
__device__ __forceinline__ void step(h2* v0, h2* v1, h2* v2, h2* v3,
                                     const h2* c0, const h2* c1, h2* med) {
    constexpr Op o = PROG.ops[I];
    if constexpr (o.kind == 0) {
        h2& A = vslot<o.a>(v0, v1, v2, v3);
        h2& B = vslot<o.b>(v0, v1, v2, v3);
        h2 lo = h2min(A, B);
        h2 hi = h2max(A, B);
        A = lo; B = hi;
    } else if constexpr (o.kind == 1) {
        vslot<o.a>(v0, v1, v2, v3) = vslot<o.b>(v0, v1, v2, v3);
    } else if constexpr (o.kind == 2) {
        vslot<o.a>(v0, v1, v2, v3) = cslot<o.b>(c0, c1);
    } else if constexpr (o.kind == 3) {
        med[o.a] = vslot<o.b>(v0, v1, v2, v3);
    } else if constexpr (o.kind == 4) {
        h2& A = vslot<o.a>(v0, v1, v2, v3);
        A = h2min(A, vslot<o.b>(v0, v1, v2, v3));
    } else if constexpr (o.kind == 5) {
        h2& B = vslot<o.b>(v0, v1, v2, v3);
        B = h2max(vslot<o.a>(v0, v1, v2, v3), B);
    } else {
        vslot<o.c>(v0, v1, v2, v3) =
            h2max(vslot<o.a>(v0, v1, v2, v3), vslot<o.b>(v0, v1, v2, v3));
    }
}

template <size_t... Is>
__device__ __forceinline__ void run_all(h2* v0, h2* v1, h2* v2, h2* v3,
                                        const h2* c0, const h2* c1, h2* med,
                                        std::index_sequence<Is...>) {
    (step<(int)Is>(v0, v1, v2, v3, c0, c1, med), ...);
}

// LDS tile: 14 rows (8 output rows + 6 halo) x 528 f16 cols.
// f16 col layout: [0..3] = left zero halo, [4..515] = image cols 0..511,
// [516..527] = right zero halo + pad. Row stride 528*2 = 1056 B (16B-mult).
#define TW 528

// Each thread: 8 (horizontal) x 2 (vertical, packed f16 halves) output pixels.
__global__ __launch_bounds__(256, 2) void median7x7_kernel(
        const float* __restrict__ img, float* __restrict__ out) {
    const int bc = blockIdx.z;
    const int tx = threadIdx.x;                    // 0..63
    const int ty = threadIdx.y;                    // 0..3
    const int tid = ty * 64 + tx;                  // 0..255
    const int yb = blockIdx.y * 8;                 // block's first output row
    const int x0 = tx * 8;                         // thread's first output col

    const float* base = img + (size_t)bc * (IMG_H * IMG_W);

    __shared__ __align__(16) _Float16 tile[14][TW];

    // ---- stage: coalesced float2 loads -> f16 pairs -> LDS ----
    const int col2 = tid * 2;                      // image cols col2, col2+1
#pragma unroll
    for (int r = 0; r < 14; ++r) {
        const int gr = yb - 3 + r;
        float f0 = 0.f, f1 = 0.f;
        if ((unsigned)gr < IMG_H) {                // wave-uniform per r
            float2 q = *(const float2*)(base + (size_t)gr * IMG_W + col2);
            f0 = q.x; f1 = q.y;
        }
        *(h2*)&tile[r][4 + col2] = (h2)__builtin_amdgcn_cvt_pkrtz(f0, f1);
        if (tid < 8) {                             // zero halos
            const int hi = (tid < 2) ? 2 * tid : 512 + 2 * tid;  // 0,2,516..526
            h2 z; z.x = (_Float16)0.f; z.y = (_Float16)0.f;
            *(h2*)&tile[r][hi] = z;
        }
    }
    __syncthreads();

    // ---- gather: conflict-free ds_read_b128 (lane-contiguous 16B) ----
    // row[k] = f16 idx [8tx .. 8tx+15]; column c uses element c+1
    // (f16 idx 8tx+1+c = 4 + (x0-3+c)).
    const int lbase = ty * 2;
    h16 row[8];
#pragma unroll
    for (int k = 0; k < 8; ++k)
        row[k] = *(const h16*)&tile[lbase + k][8 * tx];

    h2 c0[49], c1[49];
#pragma unroll
    for (int c = 0; c < 14; ++c) {
#pragma unroll
        for (int d = 0; d < 7; ++d) {
            h2 val;
            val.x = row[d][c + 1];
            val.y = row[d + 1][c + 1];
            const int idx = c * 7 + d;
            if (idx < 49) c0[idx] = val; else c1[idx - 49] = val;
        }
    }

    h2 va[64], vb[64], vc[64], vd[64];
    h2 med[8];
    run_all(va, vb, vc, vd, c0, c1, med, std::make_index_sequence<(size_t)PROG.n>{});

    const int y = yb + ty * 2;
    float* op = out + (size_t)bc * (IMG_H * IMG_W) + (size_t)y * IMG_W + x0;
    *(float4*)op = make_float4((float)med[0].x, (float)med[1].x,
                               (float)med[2].x, (float)med[3].x);
    *(float4*)(op + 4) = make_float4((float)med[4].x, (float)med[5].x,
                                     (float)med[6].x, (float)med[7].x);
    *(float4*)(op + IMG_W) = make_float4((float)med[0].y, (float)med[1].y,
                                         (float)med[2].y, (float)med[3].y);
    *(float4*)(op + IMG_W + 4) = make_float4((float)med[4].y, (float)med[5].y,
                                             (float)med[6].y, (float)med[7].y);
}

extern "C" void kernel_launch(void* const* d_in, const int* in_sizes, int n_in,
                              void* d_out, int out_size, void* d_ws, size_t ws_size,
                              hipStream_t stream) {
    const float* img = (const float*)d_in[0];
    float* out = (float*)d_out;
    dim3 grid(1, 64, 24);
    dim3 block(64, 4, 1);
    hipLaunchKernelGGL(median7x7_kernel, grid, block, 0, stream, img, out);
}

// Round 12
// 90.121 us; speedup vs baseline: 1.0683x; 1.0683x over previous
//
#include <hip/hip_runtime.h>
#include <utility>

#define IMG_H 512
#define IMG_W 512

typedef _Float16 h2 __attribute__((ext_vector_type(2)));

__device__ __forceinline__ h2 h2min(h2 a, h2 b) { return __builtin_elementwise_min(a, b); }
__device__ __forceinline__ h2 h2max(h2 a, h2 b) { return __builtin_elementwise_max(a, b); }

// ---------------------------------------------------------------------------
// Round 12: r10 kernel (mov-free compile-time program, global-load preamble —
// r11's LDS staging regressed and is reverted) with ONE change:
// __launch_bounds__(256, 3). Occupancy history: r6 default = 76 VGPR / 6
// spilling waves; r7+ (256,2) = fat waves, only 2/SIMD; both ~equal. The
// r10 program's peak live set (~130-150 VGPR) fits the (256,3) budget of
// ~170 VGPR nearly spill-free while adding +50% waves for latency hiding.
// kinds: 0 ce(a,b)  1 mov a<-b  2 load a<-cols[b]  3 store med[a]<-v[b]
//        4 a=min(a,b)  5 b=max(a,b)  7 c=max(a,b)
// ---------------------------------------------------------------------------
struct Op { int kind, a, b, c; };
constexpr int NSLOT = 512;
constexpr int MAXOPS = 4096;
struct Prog { Op ops[MAXOPS]; int n; int nphys; bool ok; };

constexpr int pow2ceil(int x) { int p = 1; while (p < x) p += p; return p; }

struct Run { int s[48]; int len; };

struct Builder {
    Op ops[MAXOPS] = {};
    int n = 0;
    int nv = 0;
    bool ok = true;

    constexpr void emit(int k, int a, int b, int c) {
        if (n < MAXOPS) ops[n++] = Op{k, a, b, c}; else ok = false;
    }
    constexpr int fresh() {
        if (nv < NSLOT) return nv++;
        ok = false; return 0;
    }
    constexpr Run load_col(int c) {
        Run r{}; r.len = 7;
        for (int i = 0; i < 7; ++i) { r.s[i] = fresh(); emit(2, r.s[i], c * 7 + i, 0); }
        for (int p = 1; p < 7; p += p)
            for (int k = p; k > 0; k /= 2)
                for (int j = k % p; j + k < 7; j += k + k)
                    for (int i = 0; i < k; ++i)
                        if (i + j + k < 7 && (i + j) / (p + p) == (i + j + k) / (p + p))
                            emit(0, r.s[i + j], r.s[i + j + k], 0);
        return r;
    }
    constexpr Run copy(const Run& a) {
        Run r{}; r.len = a.len;
        for (int i = 0; i < a.len; ++i) { r.s[i] = fresh(); emit(1, r.s[i], a.s[i], 0); }
        return r;
    }
    constexpr Run merge(const Run& A, const Run& B) {
        int P = pow2ceil(A.len > B.len ? A.len : B.len);
        if (A.len > P || B.len > P || 2 * P > 96) { ok = false; }
        int map[96] = {};
        for (int i = 0; i < 2 * P; ++i) map[i] = -1;
        for (int i = 0; i < A.len; ++i) map[i] = A.s[i];
        for (int i = 0; i < B.len; ++i) map[P + i] = B.s[i];
        for (int k = P; k > 0; k /= 2)
            for (int j = k % P; j + k < 2 * P; j += k + k)
                for (int i = 0; i < k; ++i) {
                    int x = i + j, y = i + j + k;
                    int a = map[x], b = map[y];
                    if (a >= 0 && b >= 0) emit(0, a, b, 0);
                    else if (a < 0 && b >= 0) { map[x] = b; map[y] = -1; }
                }
        Run r{}; r.len = A.len + B.len;
        for (int i = 0; i < r.len; ++i) { if (map[i] < 0) ok = false; r.s[i] = map[i]; }
        for (int i = r.len; i < 2 * P; ++i) if (map[i] >= 0) ok = false;
        return r;
    }
    constexpr void select49(const Run& A, const Run& B, int o) {
        if (A.len != 42 || B.len != 7) ok = false;
        int T[7] = {};
        for (int t = 0; t < 7; ++t) {
            T[t] = fresh();
            emit(7, A.s[17 + t], B.s[6 - t], T[t]);
        }
        emit(4, T[0], T[1], 0); emit(4, T[2], T[3], 0);
        emit(4, T[4], T[5], 0); emit(4, T[6], A.s[24], 0);
        emit(4, T[0], T[2], 0); emit(4, T[4], T[6], 0);
        emit(4, T[0], T[4], 0);
        emit(3, o, T[0], 0);
    }
};

constexpr Prog build() {
    Builder b{};
    Run g1 = b.load_col(1), g2 = b.load_col(2), g3 = b.load_col(3),
        g4 = b.load_col(4), g5 = b.load_col(5), g6 = b.load_col(6),
        g7 = b.load_col(7), g8 = b.load_col(8);
    Run g2c = b.copy(g2), g4c = b.copy(g4), g6c = b.copy(g6);

    Run M12 = b.merge(g1, g2c);
    Run M34 = b.merge(g3, g4c);
    Run M56 = b.merge(g5, g6c);
    Run M56b = b.copy(M56);
    Run C28A = b.merge(M34, M56);
    Run C28Ac = b.copy(C28A);
    Run C42A = b.merge(C28Ac, M12);
    Run g0 = b.load_col(0);
    b.select49(C42A, g0, 0);
    b.select49(C42A, g7, 1);

    Run M78 = b.merge(g7, g8);
    Run M78b = b.copy(M78);
    Run C42B = b.merge(C28A, M78);
    Run g9 = b.load_col(9);
    b.select49(C42B, g2, 2);
    b.select49(C42B, g9, 3);

    Run g10 = b.load_col(10);
    Run M910 = b.merge(g9, g10);
    Run C28B = b.merge(M78b, M910);
    Run C28Bc = b.copy(C28B);
    Run C42C = b.merge(C28Bc, M56b);
    Run g11 = b.load_col(11);
    b.select49(C42C, g4, 4);
    b.select49(C42C, g11, 5);

    Run g12 = b.load_col(12);
    Run M1112 = b.merge(g11, g12);
    Run C42D = b.merge(C28B, M1112);
    Run g13 = b.load_col(13);
    b.select49(C42D, g6, 6);
    b.select49(C42D, g13, 7);

    // ---- backward prune + min/max degradation ----
    Prog p{};
    bool needed[NSLOT] = {};
    int kindr[MAXOPS] = {};
    bool keep[MAXOPS] = {};
    for (int t = b.n - 1; t >= 0; --t) {
        Op o = b.ops[t];
        if (o.kind == 3) { keep[t] = true; kindr[t] = 3; needed[o.b] = true; }
        else if (o.kind == 0) {
            bool na = needed[o.a], nb = needed[o.b];
            if (na && nb)      { keep[t] = true; kindr[t] = 0; }
            else if (na)       { keep[t] = true; kindr[t] = 4; needed[o.b] = true; }
            else if (nb)       { keep[t] = true; kindr[t] = 5; needed[o.a] = true; }
        } else if (o.kind == 1) {
            if (needed[o.a]) { keep[t] = true; kindr[t] = 1; needed[o.a] = false; needed[o.b] = true; }
        } else if (o.kind == 2) {
            if (needed[o.a]) { keep[t] = true; kindr[t] = 2; needed[o.a] = false; }
        } else if (o.kind == 4) {
            if (needed[o.a]) { keep[t] = true; kindr[t] = 4; needed[o.b] = true; }
        } else if (o.kind == 5) {
            if (needed[o.b]) { keep[t] = true; kindr[t] = 5; needed[o.a] = true; }
        } else if (o.kind == 7) {
            if (needed[o.c]) { keep[t] = true; kindr[t] = 7; needed[o.c] = false;
                               needed[o.a] = true; needed[o.b] = true; }
        }
    }
    p.n = 0;
    for (int t = 0; t < b.n; ++t)
        if (keep[t]) { p.ops[p.n] = b.ops[t]; p.ops[p.n].kind = kindr[t]; ++p.n; }
    p.ok = b.ok;

    // ---- liveness / last-use flags ----
    bool live[NSLOT] = {};
    bool lu_a[MAXOPS] = {};
    bool lu_b[MAXOPS] = {};
    for (int t = p.n - 1; t >= 0; --t) {
        Op o = p.ops[t];
        if (o.kind == 0 || o.kind == 4 || o.kind == 5 || o.kind == 7) {
            lu_a[t] = !live[o.a]; lu_b[t] = !live[o.b];
        } else if (o.kind == 1 || o.kind == 3) {
            lu_b[t] = !live[o.b];
        }
        if (o.kind == 0) { live[o.a] = false; live[o.b] = false; }
        else if (o.kind == 1 || o.kind == 2 || o.kind == 4) live[o.a] = false;
        else if (o.kind == 5) live[o.b] = false;
        else if (o.kind == 7) live[o.c] = false;
        if (o.kind == 0 || o.kind == 4 || o.kind == 5 || o.kind == 7) {
            live[o.a] = true; live[o.b] = true;
        } else if (o.kind == 1 || o.kind == 3) live[o.b] = true;
    }
    for (int t = 0; t < p.n; ++t) {
        Op o = p.ops[t];
        if (o.kind == 0 && (lu_a[t] || lu_b[t])) p.ok = false;
        if (o.kind == 4 && lu_a[t]) p.ok = false;
        if (o.kind == 5 && lu_b[t]) p.ok = false;
    }
    // ---- linear-scan regalloc ----
    int phys[NSLOT] = {};
    bool bound[NSLOT] = {};
    int freelist[NSLOT] = {};
    int nfree = 0, nphys = 0;
    for (int t = 0; t < p.n; ++t) {
        Op o = p.ops[t];
        if (o.kind == 0) {
            if (!bound[o.a] || !bound[o.b]) p.ok = false;
            p.ops[t].a = phys[o.a]; p.ops[t].b = phys[o.b];
        } else if (o.kind == 4) {
            if (!bound[o.a] || !bound[o.b]) p.ok = false;
            p.ops[t].a = phys[o.a]; p.ops[t].b = phys[o.b];
            if (lu_b[t]) { freelist[nfree++] = phys[o.b]; bound[o.b] = false; }
        } else if (o.kind == 5) {
            if (!bound[o.a] || !bound[o.b]) p.ok = false;
            p.ops[t].a = phys[o.a]; p.ops[t].b = phys[o.b];
            if (lu_a[t]) { freelist[nfree++] = phys[o.a]; bound[o.a] = false; }
        } else if (o.kind == 7) {
            if (!bound[o.a] || !bound[o.b]) p.ok = false;
            p.ops[t].a = phys[o.a]; p.ops[t].b = phys[o.b];
            if (lu_a[t]) { freelist[nfree++] = phys[o.a]; bound[o.a] = false; }
            if (lu_b[t]) { freelist[nfree++] = phys[o.b]; bound[o.b] = false; }
            int pc = (nfree > 0) ? freelist[--nfree] : nphys++;
            phys[o.c] = pc; bound[o.c] = true;
            p.ops[t].c = pc;
        } else if (o.kind == 1) {
            if (!bound[o.b]) p.ok = false;
            int pb = phys[o.b];
            p.ops[t].b = pb;
            if (lu_b[t]) { freelist[nfree++] = pb; bound[o.b] = false; }
            int pa = (nfree > 0) ? freelist[--nfree] : nphys++;
            phys[o.a] = pa; bound[o.a] = true;
            p.ops[t].a = pa;
        } else if (o.kind == 2) {
            int pa = (nfree > 0) ? freelist[--nfree] : nphys++;
            phys[o.a] = pa; bound[o.a] = true;
            p.ops[t].a = pa;
        } else {
            if (!bound[o.b]) p.ok = false;
            p.ops[t].b = phys[o.b];
            if (lu_b[t]) { freelist[nfree++] = phys[o.b]; bound[o.b] = false; }
        }
        if (nphys > NSLOT || nfree > NSLOT) p.ok = false;
    }
    p.nphys = nphys;
    return p;
}

constexpr Prog PROG = build();
static_assert(PROG.ok, "program build failed");
static_assert(PROG.n > 300 && PROG.n < 2400, "op count out of range");
static_assert(PROG.nphys > 0 && PROG.nphys <= 256, "regalloc blew up");

// ---- banked physical frame: every alloca <= 64 elements ----
template <int P>
__device__ __forceinline__ h2& vslot(h2* v0, h2* v1, h2* v2, h2* v3) {
    if constexpr (P < 64) return v0[P];
    else if constexpr (P < 128) return v1[P - 64];
    else if constexpr (P < 192) return v2[P - 128];
    else return v3[P - 192];
}
template <int P>
__device__ __forceinline__ h2 cslot(const h2* c0, const h2* c1) {
    if constexpr (P < 49) return c0[P];
    else return c1[P - 49];
}

template <int I>
__device__ __forceinline__ void step(h2* v0, h2* v1, h2* v2, h2* v3,
                                     const h2* c0, const h2* c1, h2* med) {
    constexpr Op o = PROG.ops[I];
    if constexpr (o.kind == 0) {
        h2& A = vslot<o.a>(v0, v1, v2, v3);
        h2& B = vslot<o.b>(v0, v1, v2, v3);
        h2 lo = h2min(A, B);
        h2 hi = h2max(A, B);
        A = lo; B = hi;
    } else if constexpr (o.kind == 1) {
        vslot<o.a>(v0, v1, v2, v3) = vslot<o.b>(v0, v1, v2, v3);
    } else if constexpr (o.kind == 2) {
        vslot<o.a>(v0, v1, v2, v3) = cslot<o.b>(c0, c1);
    } else if constexpr (o.kind == 3) {
        med[o.a] = vslot<o.b>(v0, v1, v2, v3);
    } else if constexpr (o.kind == 4) {
        h2& A = vslot<o.a>(v0, v1, v2, v3);
        A = h2min(A, vslot<o.b>(v0, v1, v2, v3));
    } else if constexpr (o.kind == 5) {
        h2& B = vslot<o.b>(v0, v1, v2, v3);
        B = h2max(vslot<o.a>(v0, v1, v2, v3), B);
    } else {
        vslot<o.c>(v0, v1, v2, v3) =
            h2max(vslot<o.a>(v0, v1, v2, v3), vslot<o.b>(v0, v1, v2, v3));
    }
}

template <size_t... Is>
__device__ __forceinline__ void run_all(h2* v0, h2* v1, h2* v2, h2* v3,
                                        const h2* c0, const h2* c1, h2* med,
                                        std::index_sequence<Is...>) {
    (step<(int)Is>(v0, v1, v2, v3, c0, c1, med), ...);
}

// Each thread: 8 (horizontal) x 2 (vertical, packed f16 halves) output pixels.
// launch_bounds(256,3): ~170-VGPR budget, 3 waves/SIMD — the untested middle
// between r6 (6 spilling waves @76 VGPR) and r7+ (2 fat waves @256).
__global__ __launch_bounds__(256, 3) void median7x7_kernel(
        const float* __restrict__ img, float* __restrict__ out) {
    const int bc = blockIdx.z;
    const int tx = threadIdx.x;                    // 0..63
    const int ty = threadIdx.y;                    // 0..3
    const int x0 = (blockIdx.x * 64 + tx) * 8;     // 0..504
    const int y  = (blockIdx.y * 4 + ty) * 2;      // 0..510

    const float* base = img + (size_t)bc * (IMG_H * IMG_W);
    const bool okl = (x0 >= 4);          // false only for tx == 0
    const bool okr = (x0 <= 496);        // false only for tx == 63
    const int xl = okl ? (x0 - 4) : 0;
    const int xr = okr ? (x0 + 8) : 504;

    // Packed columns, two <=49-element banks:
    // logical colv[c*7+d] = (img[y-3+d][gc], img[y-2+d][gc]), gc = x0-3+c.
    h2 c0[49], c1[49];
    float prv[14];
#pragma unroll
    for (int r = 0; r < 8; ++r) {
        const int yy = y - 3 + r;
        float4 Q0, Q1, Q2, Q3;
        if ((unsigned)yy < IMG_H) {   // wave-uniform (blockDim.x == 64)
            const float* rp = base + (size_t)yy * IMG_W;
            Q0 = *(const float4*)(rp + xl);
            Q1 = *(const float4*)(rp + x0);
            Q2 = *(const float4*)(rp + x0 + 4);
            Q3 = *(const float4*)(rp + xr);
        } else {
            Q0 = make_float4(0.f, 0.f, 0.f, 0.f); Q1 = Q0; Q2 = Q0; Q3 = Q0;
        }
        float cur[14];
        cur[0] = okl ? Q0.y : 0.f; cur[1] = okl ? Q0.z : 0.f; cur[2] = okl ? Q0.w : 0.f;
        cur[3] = Q1.x; cur[4] = Q1.y; cur[5] = Q1.z; cur[6] = Q1.w;
        cur[7] = Q2.x; cur[8] = Q2.y; cur[9] = Q2.z; cur[10] = Q2.w;
        cur[11] = okr ? Q3.x : 0.f; cur[12] = okr ? Q3.y : 0.f; cur[13] = okr ? Q3.z : 0.f;
        if (r > 0) {
#pragma unroll
            for (int c = 0; c < 14; ++c) {
                const int idx = c * 7 + (r - 1);   // constant after unroll
                h2 val = (h2)__builtin_amdgcn_cvt_pkrtz(prv[c], cur[c]);
                if (idx < 49) c0[idx] = val; else c1[idx - 49] = val;
            }
        }
#pragma unroll
        for (int c = 0; c < 14; ++c) prv[c] = cur[c];
    }

    h2 va[64], vb[64], vc[64], vd[64];
    h2 med[8];
    run_all(va, vb, vc, vd, c0, c1, med, std::make_index_sequence<(size_t)PROG.n>{});

    float* op = out + (size_t)bc * (IMG_H * IMG_W) + (size_t)y * IMG_W + x0;
    *(float4*)op = make_float4((float)med[0].x, (float)med[1].x,
                               (float)med[2].x, (float)med[3].x);
    *(float4*)(op + 4) = make_float4((float)med[4].x, (float)med[5].x,
                                     (float)med[6].x, (float)med[7].x);
    *(float4*)(op + IMG_W) = make_float4((float)med[0].y, (float)med[1].y,
                                         (float)med[2].y, (float)med[3].y);
    *(float4*)(op + IMG_W + 4) = make_float4((float)med[4].y, (float)med[5].y,
                                             (float)med[6].y, (float)med[7].y);
}

extern "C" void kernel_launch(void* const* d_in, const int* in_sizes, int n_in,
                              void* d_out, int out_size, void* d_ws, size_t ws_size,
                              hipStream_t stream) {
    const float* img = (const float*)d_in[0];
    float* out = (float*)d_out;
    dim3 grid(1, 64, 24);
    dim3 block(64, 4, 1);
    hipLaunchKernelGGL(median7x7_kernel, grid, block, 0, stream, img, out);
}

// Round 13
// 89.695 us; speedup vs baseline: 1.0734x; 1.0047x over previous
//
#include <hip/hip_runtime.h>
#include <utility>

#define IMG_H 512
#define IMG_W 512

typedef _Float16 h2 __attribute__((ext_vector_type(2)));

__device__ __forceinline__ h2 h2min(h2 a, h2 b) { return __builtin_elementwise_min(a, b); }
__device__ __forceinline__ h2 h2max(h2 a, h2 b) { return __builtin_elementwise_max(a, b); }

// ---------------------------------------------------------------------------
// Round 13: JIT LDS COLUMN READS. Accounting shows r10's kernel carries
// ~30 us/SIMD of stall over a ~6.6 us VALU floor, insensitive to launch
// bounds (r6/r7/r12 sweep) => true live set (c-banks 98 + v-frame ~150)
// exceeds 256 VGPRs and spills to scratch regardless of budget. Fix: the
// 98 column values move to a pair-packed LDS tile; each program load op is
// ONE ds_read_b32 with compile-time immediate offset (no extract VALU —
// r11's mistake), layout pads 1 h2 per 8 cols so gather stride is 9 banks
// (odd -> 2-way, free). Column values become short-lived; spills vanish.
// Sort program = r10 (mov-free, pruned, linear-scan regalloc), unchanged.
// kinds: 0 ce(a,b)  1 mov a<-b  2 load a<-lds col  3 store med[a]<-v[b]
//        4 a=min(a,b)  5 b=max(a,b)  7 c=max(a,b)
// ---------------------------------------------------------------------------
struct Op { int kind, a, b, c; };
constexpr int NSLOT = 512;
constexpr int MAXOPS = 4096;
struct Prog { Op ops[MAXOPS]; int n; int nphys; bool ok; };

constexpr int pow2ceil(int x) { int p = 1; while (p < x) p += p; return p; }

struct Run { int s[48]; int len; };

struct Builder {
    Op ops[MAXOPS] = {};
    int n = 0;
    int nv = 0;
    bool ok = true;

    constexpr void emit(int k, int a, int b, int c) {
        if (n < MAXOPS) ops[n++] = Op{k, a, b, c}; else ok = false;
    }
    constexpr int fresh() {
        if (nv < NSLOT) return nv++;
        ok = false; return 0;
    }
    constexpr Run load_col(int c) {
        Run r{}; r.len = 7;
        for (int i = 0; i < 7; ++i) { r.s[i] = fresh(); emit(2, r.s[i], c * 7 + i, 0); }
        for (int p = 1; p < 7; p += p)
            for (int k = p; k > 0; k /= 2)
                for (int j = k % p; j + k < 7; j += k + k)
                    for (int i = 0; i < k; ++i)
                        if (i + j + k < 7 && (i + j) / (p + p) == (i + j + k) / (p + p))
                            emit(0, r.s[i + j], r.s[i + j + k], 0);
        return r;
    }
    constexpr Run copy(const Run& a) {
        Run r{}; r.len = a.len;
        for (int i = 0; i < a.len; ++i) { r.s[i] = fresh(); emit(1, r.s[i], a.s[i], 0); }
        return r;
    }
    constexpr Run merge(const Run& A, const Run& B) {
        int P = pow2ceil(A.len > B.len ? A.len : B.len);
        if (A.len > P || B.len > P || 2 * P > 96) { ok = false; }
        int map[96] = {};
        for (int i = 0; i < 2 * P; ++i) map[i] = -1;
        for (int i = 0; i < A.len; ++i) map[i] = A.s[i];
        for (int i = 0; i < B.len; ++i) map[P + i] = B.s[i];
        for (int k = P; k > 0; k /= 2)
            for (int j = k % P; j + k < 2 * P; j += k + k)
                for (int i = 0; i < k; ++i) {
                    int x = i + j, y = i + j + k;
                    int a = map[x], b = map[y];
                    if (a >= 0 && b >= 0) emit(0, a, b, 0);
                    else if (a < 0 && b >= 0) { map[x] = b; map[y] = -1; }
                }
        Run r{}; r.len = A.len + B.len;
        for (int i = 0; i < r.len; ++i) { if (map[i] < 0) ok = false; r.s[i] = map[i]; }
        for (int i = r.len; i < 2 * P; ++i) if (map[i] >= 0) ok = false;
        return r;
    }
    constexpr void select49(const Run& A, const Run& B, int o) {
        if (A.len != 42 || B.len != 7) ok = false;
        int T[7] = {};
        for (int t = 0; t < 7; ++t) {
            T[t] = fresh();
            emit(7, A.s[17 + t], B.s[6 - t], T[t]);
        }
        emit(4, T[0], T[1], 0); emit(4, T[2], T[3], 0);
        emit(4, T[4], T[5], 0); emit(4, T[6], A.s[24], 0);
        emit(4, T[0], T[2], 0); emit(4, T[4], T[6], 0);
        emit(4, T[0], T[4], 0);
        emit(3, o, T[0], 0);
    }
};

constexpr Prog build() {
    Builder b{};
    Run g1 = b.load_col(1), g2 = b.load_col(2), g3 = b.load_col(3),
        g4 = b.load_col(4), g5 = b.load_col(5), g6 = b.load_col(6),
        g7 = b.load_col(7), g8 = b.load_col(8);
    Run g2c = b.copy(g2), g4c = b.copy(g4), g6c = b.copy(g6);

    Run M12 = b.merge(g1, g2c);
    Run M34 = b.merge(g3, g4c);
    Run M56 = b.merge(g5, g6c);
    Run M56b = b.copy(M56);
    Run C28A = b.merge(M34, M56);
    Run C28Ac = b.copy(C28A);
    Run C42A = b.merge(C28Ac, M12);
    Run g0 = b.load_col(0);
    b.select49(C42A, g0, 0);
    b.select49(C42A, g7, 1);

    Run M78 = b.merge(g7, g8);
    Run M78b = b.copy(M78);
    Run C42B = b.merge(C28A, M78);
    Run g9 = b.load_col(9);
    b.select49(C42B, g2, 2);
    b.select49(C42B, g9, 3);

    Run g10 = b.load_col(10);
    Run M910 = b.merge(g9, g10);
    Run C28B = b.merge(M78b, M910);
    Run C28Bc = b.copy(C28B);
    Run C42C = b.merge(C28Bc, M56b);
    Run g11 = b.load_col(11);
    b.select49(C42C, g4, 4);
    b.select49(C42C, g11, 5);

    Run g12 = b.load_col(12);
    Run M1112 = b.merge(g11, g12);
    Run C42D = b.merge(C28B, M1112);
    Run g13 = b.load_col(13);
    b.select49(C42D, g6, 6);
    b.select49(C42D, g13, 7);

    // ---- backward prune + min/max degradation ----
    Prog p{};
    bool needed[NSLOT] = {};
    int kindr[MAXOPS] = {};
    bool keep[MAXOPS] = {};
    for (int t = b.n - 1; t >= 0; --t) {
        Op o = b.ops[t];
        if (o.kind == 3) { keep[t] = true; kindr[t] = 3; needed[o.b] = true; }
        else if (o.kind == 0) {
            bool na = needed[o.a], nb = needed[o.b];
            if (na && nb)      { keep[t] = true; kindr[t] = 0; }
            else if (na)       { keep[t] = true; kindr[t] = 4; needed[o.b] = true; }
            else if (nb)       { keep[t] = true; kindr[t] = 5; needed[o.a] = true; }
        } else if (o.kind == 1) {
            if (needed[o.a]) { keep[t] = true; kindr[t] = 1; needed[o.a] = false; needed[o.b] = true; }
        } else if (o.kind == 2) {
            if (needed[o.a]) { keep[t] = true; kindr[t] = 2; needed[o.a] = false; }
        } else if (o.kind == 4) {
            if (needed[o.a]) { keep[t] = true; kindr[t] = 4; needed[o.b] = true; }
        } else if (o.kind == 5) {
            if (needed[o.b]) { keep[t] = true; kindr[t] = 5; needed[o.a] = true; }
        } else if (o.kind == 7) {
            if (needed[o.c]) { keep[t] = true; kindr[t] = 7; needed[o.c] = false;
                               needed[o.a] = true; needed[o.b] = true; }
        }
    }
    p.n = 0;
    for (int t = 0; t < b.n; ++t)
        if (keep[t]) { p.ops[p.n] = b.ops[t]; p.ops[p.n].kind = kindr[t]; ++p.n; }
    p.ok = b.ok;

    // ---- liveness / last-use flags ----
    bool live[NSLOT] = {};
    bool lu_a[MAXOPS] = {};
    bool lu_b[MAXOPS] = {};
    for (int t = p.n - 1; t >= 0; --t) {
        Op o = p.ops[t];
        if (o.kind == 0 || o.kind == 4 || o.kind == 5 || o.kind == 7) {
            lu_a[t] = !live[o.a]; lu_b[t] = !live[o.b];
        } else if (o.kind == 1 || o.kind == 3) {
            lu_b[t] = !live[o.b];
        }
        if (o.kind == 0) { live[o.a] = false; live[o.b] = false; }
        else if (o.kind == 1 || o.kind == 2 || o.kind == 4) live[o.a] = false;
        else if (o.kind == 5) live[o.b] = false;
        else if (o.kind == 7) live[o.c] = false;
        if (o.kind == 0 || o.kind == 4 || o.kind == 5 || o.kind == 7) {
            live[o.a] = true; live[o.b] = true;
        } else if (o.kind == 1 || o.kind == 3) live[o.b] = true;
    }
    for (int t = 0; t < p.n; ++t) {
        Op o = p.ops[t];
        if (o.kind == 0 && (lu_a[t] || lu_b[t])) p.ok = false;
        if (o.kind == 4 && lu_a[t]) p.ok = false;
        if (o.kind == 5 && lu_b[t]) p.ok = false;
    }
    // ---- linear-scan regalloc ----
    int phys[NSLOT] = {};
    bool bound[NSLOT] = {};
    int freelist[NSLOT] = {};
    int nfree = 0, nphys = 0;
    for (int t = 0; t < p.n; ++t) {
        Op o = p.ops[t];
        if (o.kind == 0) {
            if (!bound[o.a] || !bound[o.b]) p.ok = false;
            p.ops[t].a = phys[o.a]; p.ops[t].b = phys[o.b];
        } else if (o.kind == 4) {
            if (!bound[o.a] || !bound[o.b]) p.ok = false;
            p.ops[t].a = phys[o.a]; p.ops[t].b = phys[o.b];
            if (lu_b[t]) { freelist[nfree++] = phys[o.b]; bound[o.b] = false; }
        } else if (o.kind == 5) {
            if (!bound[o.a] || !bound[o.b]) p.ok = false;
            p.ops[t].a = phys[o.a]; p.ops[t].b = phys[o.b];
            if (lu_a[t]) { freelist[nfree++] = phys[o.a]; bound[o.a] = false; }
        } else if (o.kind == 7) {
            if (!bound[o.a] || !bound[o.b]) p.ok = false;
            p.ops[t].a = phys[o.a]; p.ops[t].b = phys[o.b];
            if (lu_a[t]) { freelist[nfree++] = phys[o.a]; bound[o.a] = false; }
            if (lu_b[t]) { freelist[nfree++] = phys[o.b]; bound[o.b] = false; }
            int pc = (nfree > 0) ? freelist[--nfree] : nphys++;
            phys[o.c] = pc; bound[o.c] = true;
            p.ops[t].c = pc;
        } else if (o.kind == 1) {
            if (!bound[o.b]) p.ok = false;
            int pb = phys[o.b];
            p.ops[t].b = pb;
            if (lu_b[t]) { freelist[nfree++] = pb; bound[o.b] = false; }
            int pa = (nfree > 0) ? freelist[--nfree] : nphys++;
            phys[o.a] = pa; bound[o.a] = true;
            p.ops[t].a = pa;
        } else if (o.kind == 2) {
            int pa = (nfree > 0) ? freelist[--nfree] : nphys++;
            phys[o.a] = pa; bound[o.a] = true;
            p.ops[t].a = pa;
        } else {
            if (!bound[o.b]) p.ok = false;
            p.ops[t].b = phys[o.b];
            if (lu_b[t]) { freelist[nfree++] = phys[o.b]; bound[o.b] = false; }
        }
        if (nphys > NSLOT || nfree > NSLOT) p.ok = false;
    }
    p.nphys = nphys;
    return p;
}

constexpr Prog PROG = build();
static_assert(PROG.ok, "program build failed");
static_assert(PROG.n > 300 && PROG.n < 2400, "op count out of range");
static_assert(PROG.nphys > 0 && PROG.nphys <= 224, "regalloc blew up");

// ---- banked physical frame: every alloca <= 64 elements ----
template <int P>
__device__ __forceinline__ h2& vslot(h2* v0, h2* v1, h2* v2, h2* v3) {
    if constexpr (P < 64) return v0[P];
    else if constexpr (P < 128) return v1[P - 64];
    else if constexpr (P < 192) return v2[P - 128];
    else return v3[P - 192];
}

// LDS pair-row tile: 13 pair-rows x 594 h2. Pair-row p holds
// h2(row yb-3+p, row yb-3+p+1). Logical col L = image_x + 3 maps to
// physical L + L/8 (1 pad h2 per 8 cols -> gather stride 9 banks, odd).
#define LROW 594

template <int I>
__device__ __forceinline__ void step(h2* v0, h2* v1, h2* v2, h2* v3,
                                     const h2* __restrict__ ldsg, h2* med) {
    constexpr Op o = PROG.ops[I];
    if constexpr (o.kind == 0) {
        h2& A = vslot<o.a>(v0, v1, v2, v3);
        h2& B = vslot<o.b>(v0, v1, v2, v3);
        h2 lo = h2min(A, B);
        h2 hi = h2max(A, B);
        A = lo; B = hi;
    } else if constexpr (o.kind == 1) {
        vslot<o.a>(v0, v1, v2, v3) = vslot<o.b>(v0, v1, v2, v3);
    } else if constexpr (o.kind == 2) {
        // column c, element i: one ds_read_b32 at compile-time offset.
        constexpr int cc = o.b / 7, ii = o.b % 7;
        constexpr int off = ii * LROW + cc + (cc >= 8 ? 1 : 0);
        vslot<o.a>(v0, v1, v2, v3) = ldsg[off];
    } else if constexpr (o.kind == 3) {
        med[o.a] = vslot<o.b>(v0, v1, v2, v3);
    } else if constexpr (o.kind == 4) {
        h2& A = vslot<o.a>(v0, v1, v2, v3);
        A = h2min(A, vslot<o.b>(v0, v1, v2, v3));
    } else if constexpr (o.kind == 5) {
        h2& B = vslot<o.b>(v0, v1, v2, v3);
        B = h2max(vslot<o.a>(v0, v1, v2, v3), B);
    } else {
        vslot<o.c>(v0, v1, v2, v3) =
            h2max(vslot<o.a>(v0, v1, v2, v3), vslot<o.b>(v0, v1, v2, v3));
    }
}

template <size_t... Is>
__device__ __forceinline__ void run_all(h2* v0, h2* v1, h2* v2, h2* v3,
                                        const h2* __restrict__ ldsg, h2* med,
                                        std::index_sequence<Is...>) {
    (step<(int)Is>(v0, v1, v2, v3, ldsg, med), ...);
}

// Each thread: 8 (horizontal) x 2 (vertical, packed f16 halves) output pixels.
__global__ __launch_bounds__(256, 2) void median7x7_kernel(
        const float* __restrict__ img, float* __restrict__ out) {
    const int bc = blockIdx.z;
    const int tx = threadIdx.x;                    // 0..63
    const int ty = threadIdx.y;                    // 0..3
    const int tid = ty * 64 + tx;                  // 0..255
    const int yb = blockIdx.y * 8;                 // block's first output row
    const int x0 = tx * 8;                         // thread's first output col

    const float* base = img + (size_t)bc * (IMG_H * IMG_W);

    __shared__ h2 lds[13 * LROW];                  // 30.9 KB

    // ---- stage: coalesced float2 loads -> f16 pairs -> pair-row LDS ----
    const int cA = 2 * tid;                        // image cols cA, cA+1
    h2 pk[14];
#pragma unroll
    for (int r = 0; r < 14; ++r) {
        const int gr = yb - 3 + r;
        float f0 = 0.f, f1 = 0.f;
        if ((unsigned)gr < IMG_H) {                // wave-uniform per r
            float2 q = *(const float2*)(base + (size_t)gr * IMG_W + cA);
            f0 = q.x; f1 = q.y;
        }
        pk[r] = (h2)__builtin_amdgcn_cvt_pkrtz(f0, f1);
    }
    const int LA = cA + 3, LB = cA + 4;            // logical cols
    const int pA = LA + (LA >> 3), pB = LB + (LB >> 3);
#pragma unroll
    for (int p = 0; p < 13; ++p) {
        h2 va; va.x = pk[p].x; va.y = pk[p + 1].x;
        h2 vb; vb.x = pk[p].y; vb.y = pk[p + 1].y;
        lds[p * LROW + pA] = va;
        lds[p * LROW + pB] = vb;
    }
    if (tid < 78) {                                // zero halos: logical 0..2, 515..517
        const int row = tid / 6, w = tid % 6;
        const int ph = (w < 3) ? w : (579 + (w - 3));
        h2 z; z.x = (_Float16)0.f; z.y = (_Float16)0.f;
        lds[row * LROW + ph] = z;
    }
    __syncthreads();

    // gather base: pair-row 2ty, physical col of logical x0 (= 9*tx)
    const h2* ldsg = &lds[(2 * ty) * LROW + 9 * tx];

    h2 va[64], vb[64], vc[64], vd[64];
    h2 med[8];
    run_all(va, vb, vc, vd, ldsg, med, std::make_index_sequence<(size_t)PROG.n>{});

    const int y = yb + ty * 2;
    float* op = out + (size_t)bc * (IMG_H * IMG_W) + (size_t)y * IMG_W + x0;
    *(float4*)op = make_float4((float)med[0].x, (float)med[1].x,
                               (float)med[2].x, (float)med[3].x);
    *(float4*)(op + 4) = make_float4((float)med[4].x, (float)med[5].x,
                                     (float)med[6].x, (float)med[7].x);
    *(float4*)(op + IMG_W) = make_float4((float)med[0].y, (float)med[1].y,
                                         (float)med[2].y, (float)med[3].y);
    *(float4*)(op + IMG_W + 4) = make_float4((float)med[4].y, (float)med[5].y,
                                             (float)med[6].y, (float)med[7].y);
}

extern "C" void kernel_launch(void* const* d_in, const int* in_sizes, int n_in,
                              void* d_out, int out_size, void* d_ws, size_t ws_size,
                              hipStream_t stream) {
    const float* img = (const float*)d_in[0];
    float* out = (float*)d_out;
    dim3 grid(1, 64, 24);
    dim3 block(64, 4, 1);
    hipLaunchKernelGGL(median7x7_kernel, grid, block, 0, stream, img, out);
}